// Round 20
// baseline (744.840 us; speedup 1.0000x reference)
//
#include <hip/hip_runtime.h>
#include <hip/hip_bf16.h>
#include <math.h>

// Problem constants
#define BQ   16384        // windows
#define CH   512
#define NH   8
#define HID  2048
#define NTOK (BQ*4)       // 65536 rows

using bf16 = __hip_bfloat16;
typedef __bf16 bf16x8 __attribute__((ext_vector_type(8)));
typedef float  f32x4  __attribute__((ext_vector_type(4)));

#define FENCE() asm volatile("" ::: "memory")

__device__ __forceinline__ void gload16(const void* g, void* l) {
    __builtin_amdgcn_global_load_lds(
        (const __attribute__((address_space(1))) void*)g,
        (__attribute__((address_space(3))) void*)l, 16, 0, 0);
}

// ---------------- weight packs ----------------------------------------------
// OLD format (qkv/proj, for gemm256x128): 8KB slab per (cb of 128 rows, K-32)
__device__ __forceinline__ void packw_one(const float* Wsrc, bf16* out, int q, int K) {
    int NSk = K >> 5;
    int l  = q & 63;
    int jj = (q >> 6) & 1;
    int w  = (q >> 7) & 3;
    int s  = (q >> 9) % NSk;
    int cb = q / (NSk * 512);
    int row = cb * 128 + w * 32 + jj * 16 + (l >> 2);
    int k   = s * 32 + ((l & 3) ^ ((l >> 3) & 3)) * 8;
    const float* src = Wsrc + (size_t)row * K + k;
    float4 v0 = *(const float4*)src;
    float4 v1 = *(const float4*)(src + 4);
    __align__(16) bf16 t[8];
    t[0] = __float2bfloat16(v0.x); t[1] = __float2bfloat16(v0.y);
    t[2] = __float2bfloat16(v0.z); t[3] = __float2bfloat16(v0.w);
    t[4] = __float2bfloat16(v1.x); t[5] = __float2bfloat16(v1.y);
    t[6] = __float2bfloat16(v1.z); t[7] = __float2bfloat16(v1.w);
    *(uint4*)&out[(size_t)q * 8] = *(const uint4*)t;
}

// NEW format (fc1/fc2, for gemm64): 16KB B-half slab per (cb of 256 rows, kt of 64, h):
//   chunk c = ((cb*NKT + kt)*2 + h)*1024 + r*8 + j   (r<128, j<8)
//   content = W[cb*256 + h*128 + r][kt*64 + (j^(r&7))*8 ..+8]
// (verified on fc2 in round 19)
__device__ __forceinline__ void pack64_one(const float* Wsrc, bf16* out, int q, int K) {
    int NKT = K >> 6;
    int j  = q & 7;
    int r  = (q >> 3) & 127;
    int h  = (q >> 10) & 1;
    int kt = (q >> 11) % NKT;
    int cb = q / (NKT << 11);
    int row = cb * 256 + h * 128 + r;
    int col = kt * 64 + (j ^ (r & 7)) * 8;
    const float* src = Wsrc + (size_t)row * K + col;
    float4 v0 = *(const float4*)src;
    float4 v1 = *(const float4*)(src + 4);
    __align__(16) bf16 t[8];
    t[0] = __float2bfloat16(v0.x); t[1] = __float2bfloat16(v0.y);
    t[2] = __float2bfloat16(v0.z); t[3] = __float2bfloat16(v0.w);
    t[4] = __float2bfloat16(v1.x); t[5] = __float2bfloat16(v1.y);
    t[6] = __float2bfloat16(v1.z); t[7] = __float2bfloat16(v1.w);
    *(uint4*)&out[(size_t)q * 8] = *(const uint4*)t;
}

// chunk counts: qkv 98304, proj 32768 (old); fc1 131072, fc2 131072 (new) = 393216
__global__ __launch_bounds__(256)
void packall(const float* qkv_w, const float* proj_w,
             const float* fc1_w, const float* fc2_w,
             bf16* wQKV, bf16* wPROJ, bf16* wFC1, bf16* wFC2) {
    int q = blockIdx.x * 256 + threadIdx.x;
    if (q < 98304)            packw_one(qkv_w,  wQKV,  q,           512);
    else if (q < 131072)      packw_one(proj_w, wPROJ, q - 98304,   512);
    else if (q < 262144)      pack64_one(fc1_w, wFC1,  q - 131072,  512);
    else                      pack64_one(fc2_w, wFC2,  q - 262144, 2048);
}

// ---------------- LayerNorm (fp32 or bf16 in, bf16 out), one wave per row ------
template<int BF16IN>
__global__ __launch_bounds__(256) void ln_kernel(const void* __restrict__ xin,
                                                 const float* __restrict__ g,
                                                 const float* __restrict__ b,
                                                 bf16* __restrict__ out) {
    int row  = blockIdx.x * 4 + (threadIdx.x >> 6);
    int lane = threadIdx.x & 63;
    int c0 = lane * 8;
    float f[8];
    if (BF16IN) {
        const bf16* xr = (const bf16*)xin + (size_t)row * CH;
        union { uint4 u4; bf16 h[8]; } uu;
        uu.u4 = *(const uint4*)&xr[c0];
#pragma unroll
        for (int i = 0; i < 8; ++i) f[i] = __bfloat162float(uu.h[i]);
    } else {
        const float* xr = (const float*)xin + (size_t)row * CH;
        float4 v0 = *(const float4*)&xr[c0];
        float4 v1 = *(const float4*)&xr[c0 + 4];
        f[0]=v0.x; f[1]=v0.y; f[2]=v0.z; f[3]=v0.w;
        f[4]=v1.x; f[5]=v1.y; f[6]=v1.z; f[7]=v1.w;
    }
    float s = 0.f, sq = 0.f;
#pragma unroll
    for (int i = 0; i < 8; ++i) { s += f[i]; sq += f[i] * f[i]; }
#pragma unroll
    for (int off = 32; off >= 1; off >>= 1) {
        s  += __shfl_xor(s,  off, 64);
        sq += __shfl_xor(sq, off, 64);
    }
    float mu  = s * (1.0f / CH);
    float var = sq * (1.0f / CH) - mu * mu;
    float rs  = rsqrtf(var + 1e-5f);
    float4 g0 = *(const float4*)&g[c0];
    float4 g1 = *(const float4*)&g[c0 + 4];
    float4 b0 = *(const float4*)&b[c0];
    float4 b1 = *(const float4*)&b[c0 + 4];
    float gg[8] = {g0.x,g0.y,g0.z,g0.w,g1.x,g1.y,g1.z,g1.w};
    float bb[8] = {b0.x,b0.y,b0.z,b0.w,b1.x,b1.y,b1.z,b1.w};
    __align__(16) bf16 t[8];
#pragma unroll
    for (int i = 0; i < 8; ++i)
        t[i] = __float2bfloat16((f[i] - mu) * rs * gg[i] + bb[i]);
    *(uint4*)&out[(size_t)row * CH + c0] = *(const uint4*)t;
}

// ---------------- GEMM 256x128 tile (proven, rounds 15-17) ---------------------
template<int EPI>
__global__ __launch_bounds__(512, 4)
void gemm256x128(const bf16* __restrict__ A, const bf16* __restrict__ Bp,
                 int M, int N, int K, int nbx,
                 const float* __restrict__ bias,
                 const float* residF, const bf16* residB,
                 float* outF, bf16* __restrict__ outB) {
    __shared__ __align__(16) char lds[49152];
    const int tid  = threadIdx.x;
    const int w    = tid >> 6;
    const int lane = tid & 63;
    const int nb  = gridDim.x;
    const int id  = blockIdx.x;
    const int swz = (id & 7) * (nb >> 3) + (id >> 3);
    const int bx  = swz % nbx, by = swz / nbx;
    const int bm = by * 256, bn = bx * 128;
    const int wrq = w >> 1;
    const int wch = w & 1;
    const int NSk = K >> 5;

    const int rl  = lane >> 2;
    const int kpe = ((lane & 3) ^ ((lane >> 3) & 3)) * 8;
    const bf16* gA0 = A + (size_t)(bm + w * 32 + rl) * K + kpe;
    const bf16* gA1 = gA0 + (size_t)16 * K;
    const bf16* gB = Bp + (size_t)(bn >> 7) * NSk * 4096 + w * 512 + lane * 8;

    const int kslot = ((lane >> 4) ^ ((lane >> 1) & 3));
    const int aoff = (wrq * 64 + (lane & 15)) * 64 + kslot * 16;
    const int boff = 16384 + (wch * 64 + (lane & 15)) * 64 + kslot * 16;

    f32x4 acc[4][4] = {};

    auto stage = [&](int s) {
        char* base = (char*)lds + (s & 1) * 24576;
        gload16(gA0 + (size_t)s * 32, base + w * 2048);
        gload16(gA1 + (size_t)s * 32, base + w * 2048 + 1024);
        gload16(gB  + (size_t)s * 4096, base + 16384 + w * 1024);
    };

    auto compute = [&](int slot) {
        const char* base = (const char*)lds + slot * 24576;
        bf16x8 av[4], bv[4];
#pragma unroll
        for (int n = 0; n < 4; ++n)
            bv[n] = *(const bf16x8*)(base + boff + n * 1024);
#pragma unroll
        for (int m = 0; m < 4; ++m)
            av[m] = *(const bf16x8*)(base + aoff + m * 1024);
#pragma unroll
        for (int m = 0; m < 4; ++m)
#pragma unroll
            for (int n = 0; n < 4; ++n)
                acc[m][n] = __builtin_amdgcn_mfma_f32_16x16x32_bf16(av[m], bv[n], acc[m][n], 0, 0, 0);
    };

#define WAITV(n) asm volatile("s_waitcnt vmcnt(" #n ")" ::: "memory")
    stage(0);
    for (int s = 0; s < NSk - 1; ++s) {
        stage(s + 1);
        WAITV(3);
        __builtin_amdgcn_s_barrier();
        FENCE();
        compute(s & 1);
        FENCE();
        __builtin_amdgcn_s_barrier();
    }
    WAITV(0);
    __builtin_amdgcn_s_barrier();
    FENCE();
    compute((NSk - 1) & 1);
#undef WAITV

    const int erow0 = bm + wrq * 64 + (lane >> 4) * 4;
    const int ecol0 = bn + wch * 64 + (lane & 15);
#pragma unroll
    for (int m = 0; m < 4; ++m) {
#pragma unroll
        for (int n = 0; n < 4; ++n) {
            int col = ecol0 + n * 16;
#pragma unroll
            for (int r = 0; r < 4; ++r) {
                int row = erow0 + m * 16 + r;
                size_t idx = (size_t)row * N + col;
                float v = acc[m][n][r];
                if (EPI == 0) {
                    outB[idx] = __float2bfloat16(v);
                } else if (EPI == 1) {
                    outF[idx] = v + bias[col] + residF[idx];
                } else if (EPI == 2) {
                    float t = v + bias[col];
                    float u2 = 1.5957691216f * t * (1.0f + 0.044715f * t * t);
                    float e = __expf(u2);
                    float rcp = __builtin_amdgcn_rcpf(e + 1.0f);
                    outB[idx] = __float2bfloat16(t - t * rcp);
                } else if (EPI == 3) {
                    outB[idx] = __float2bfloat16(v + bias[col] + residF[idx]);
                } else {
                    outF[idx] = v + bias[col] + __bfloat162float(residB[idx]);
                }
            }
        }
    }
}

// ---------------- GEMM64: 256x256, BK=64, 4 quadrant-phases (verified R19) -----
// EPI 1: outF = acc+bias+residF; EPI 2: outB = bf16(gelu(acc+bias)) via v_rcp;
// EPI 4: outF = acc+bias+float(residB).
template<int EPI>
__global__ __launch_bounds__(512, 2)
void gemm64(const bf16* __restrict__ A, const bf16* __restrict__ Bp,
            int M, int N, int K, int nbx,
            const float* __restrict__ bias,
            const float* residF, const bf16* residB,
            float* outF, bf16* __restrict__ outB) {
    __shared__ __align__(16) char lds[131072];
    const int tid  = threadIdx.x;
    const int w    = tid >> 6;     // wave 0..7
    const int lane = tid & 63;

    const int nb  = gridDim.x;
    const int id  = blockIdx.x;
    const int swz = (id & 7) * (nb >> 3) + (id >> 3);
    const int bx  = swz % nbx, by = swz / nbx;
    const int bm = by * 256, bn = bx * 256;
    const int wr = w >> 2;         // 0..1 (M half of 128 rows)
    const int wc = w & 3;          // 0..3 (N quarter of 64 cols)
    const int NT = K >> 6;         // K/64 tiles (>= 4)

    // A staging source (row-major A, pre-swizzled k-part)
    const bf16* gA0 = A + (size_t)(bm + w * 16 + (lane >> 3)) * K
                        + ((lane & 7) ^ ((lane >> 3) & 7)) * 8;
    // B staging source (pack64)
    const bf16* gB0 = Bp + (size_t)(bn >> 8) * NT * 16384 + w * 1024 + lane * 8;

    // fragment read offsets
    const int abase_off = wr * 16384 + (lane & 15) * 128;
    const int bbase_off = 32768 + (wc >> 1) * 16384 + ((wc & 1) * 64 + (lane & 15)) * 128;
    const int aj0 = (((lane >> 4)    ) ^ (lane & 7)) * 16;
    const int aj1 = (((lane >> 4) + 4) ^ (lane & 7)) * 16;

    f32x4 acc[8][4] = {};
    bf16x8 av[4][2], bv[2][2], bw[2][2];

    auto stA = [&](int X, int ah) {
        char* d = (char*)lds + (X & 1) * 65536 + ah * 16384 + w * 2048;
        const bf16* s = gA0 + (size_t)ah * 128 * K + (size_t)X * 64;
        gload16(s, d);
        gload16(s + (size_t)8 * K, d + 1024);
    };
    auto stB = [&](int X, int bh) {
        char* d = (char*)lds + (X & 1) * 65536 + 32768 + bh * 16384 + w * 2048;
        const bf16* s = gB0 + ((size_t)X * 2 + bh) * 8192;
        gload16(s, d);
        gload16(s + 512, d + 1024);
    };

#define RD_A(MH) { const char* _p = bb + abase_off + (MH) * 8192;            \
    _Pragma("unroll") for (int _m = 0; _m < 4; ++_m) {                       \
        av[_m][0] = *(const bf16x8*)(_p + _m * 2048 + aj0);                  \
        av[_m][1] = *(const bf16x8*)(_p + _m * 2048 + aj1); } }
#define RD_B(BV, NB) { const char* _p = bb + bbase_off + (NB) * 2048;        \
    BV[0][0] = *(const bf16x8*)(_p + aj0);                                   \
    BV[0][1] = *(const bf16x8*)(_p + aj1);                                   \
    BV[1][0] = *(const bf16x8*)(_p + 2048 + aj0);                            \
    BV[1][1] = *(const bf16x8*)(_p + 2048 + aj1); }
#define MQ(BV, MB, NB) { __builtin_amdgcn_s_setprio(1);                      \
    _Pragma("unroll") for (int _m = 0; _m < 4; ++_m)                         \
    _Pragma("unroll") for (int _n = 0; _n < 2; ++_n) {                       \
        acc[(MB)+_m][(NB)+_n] = __builtin_amdgcn_mfma_f32_16x16x32_bf16(     \
            av[_m][0], BV[_n][0], acc[(MB)+_m][(NB)+_n], 0, 0, 0);           \
        acc[(MB)+_m][(NB)+_n] = __builtin_amdgcn_mfma_f32_16x16x32_bf16(     \
            av[_m][1], BV[_n][1], acc[(MB)+_m][(NB)+_n], 0, 0, 0); }         \
    __builtin_amdgcn_s_setprio(0); }
#define WAITV2() asm volatile("s_waitcnt vmcnt(2)" ::: "memory")
#define WAITV0() asm volatile("s_waitcnt vmcnt(0)" ::: "memory")
#define SBAR()   __builtin_amdgcn_s_barrier()
#define LGKM0()  asm volatile("s_waitcnt lgkmcnt(0)" ::: "memory")

#define ITER_BODY(T, DO_ST1, DO_ST2, TAILW)                                  \
    { const char* bb = (const char*)lds + ((T) & 1) * 65536;                 \
      RD_A(0); RD_B(bv, 0); FENCE();                                        \
      if (DO_ST1) stA((T) + 1, 1);                                           \
      SBAR(); LGKM0(); MQ(bv, 0, 0); SBAR();                                 \
      RD_B(bw, 2); FENCE();                                                  \
      if (DO_ST1) stB((T) + 1, 0);                                           \
      SBAR(); LGKM0(); MQ(bw, 0, 2); SBAR();                                 \
      RD_A(1); FENCE();                                                      \
      if (DO_ST1) stB((T) + 1, 1);                                           \
      SBAR(); LGKM0(); MQ(bv, 4, 0); SBAR();                                 \
      if (DO_ST2) stA((T) + 2, 0);                                           \
      MQ(bw, 4, 2);                                                          \
      TAILW; SBAR(); }

    // prologue: tile 0 fully + A0(1); trailing wait validates tile 0
    stA(0, 0); stA(0, 1); stB(0, 0); stB(0, 1); stA(1, 0);
    WAITV2(); SBAR();

    for (int t = 0; t < NT - 2; ++t)
        ITER_BODY(t, true, true, WAITV2())
    ITER_BODY(NT - 2, true, false, WAITV0())
    {
        const char* bb = (const char*)lds + ((NT - 1) & 1) * 65536;
        RD_A(0); RD_B(bv, 0); FENCE();
        SBAR(); LGKM0(); MQ(bv, 0, 0); SBAR();
        RD_B(bw, 2); FENCE();
        SBAR(); LGKM0(); MQ(bw, 0, 2); SBAR();
        RD_A(1); FENCE();
        SBAR(); LGKM0(); MQ(bv, 4, 0); SBAR();
        MQ(bw, 4, 2);
    }
#undef RD_A
#undef RD_B
#undef MQ
#undef WAITV2
#undef WAITV0
#undef SBAR
#undef LGKM0
#undef ITER_BODY

    // epilogue: acc[mf][nf]: row = bm + wr*128 + mf*16 + (lane>>4)*4 + r,
    //                        col = bn + wc*64 + nf*16 + (lane&15)
    const int erow0 = bm + wr * 128 + (lane >> 4) * 4;
    const int ecol0 = bn + wc * 64 + (lane & 15);
#pragma unroll
    for (int m = 0; m < 8; ++m) {
#pragma unroll
        for (int n = 0; n < 4; ++n) {
            int col = ecol0 + n * 16;
#pragma unroll
            for (int r = 0; r < 4; ++r) {
                int row = erow0 + m * 16 + r;
                size_t idx = (size_t)row * N + col;
                float v = acc[m][n][r];
                if (EPI == 1) {
                    outF[idx] = v + bias[col] + residF[idx];
                } else if (EPI == 2) {
                    // tanh-form GELU via single v_rcp: out = t - t/(e+1)
                    float t = v + bias[col];
                    float u2 = 1.5957691216f * t * (1.0f + 0.044715f * t * t);
                    float e = __expf(u2);
                    float rcp = __builtin_amdgcn_rcpf(e + 1.0f);
                    outB[idx] = __float2bfloat16(t - t * rcp);
                } else {  // EPI 4
                    outF[idx] = v + bias[col] + __bfloat162float(residB[idx]);
                }
            }
        }
    }
}

// ---------------- windowed attention: one block per window ----------------
__global__ __launch_bounds__(256)
void attn_kernel(const bf16* __restrict__ qkv, const float* __restrict__ rpb,
                 bf16* __restrict__ o) {
    __shared__ __align__(16) bf16 sT[4 * 1536];
    __shared__ float sS[NH][4][4];
    __shared__ float sP[NH][4][4];
    int b   = blockIdx.x;
    int tid = threadIdx.x;
    const bf16* src = qkv + (size_t)b * (4 * 1536);
#pragma unroll
    for (int it = 0; it < 3; ++it) {
        int e = (it * 256 + tid) * 8;
        *(uint4*)&sT[e] = *(const uint4*)&src[e];
    }
    __syncthreads();
    if (tid < 128) {
        int h = tid >> 4, i = (tid >> 2) & 3, j = tid & 3;
        const bf16* q = &sT[i * 1536 + h * 64];
        const bf16* k = &sT[j * 1536 + 512 + h * 64];
        float acc = 0.f;
#pragma unroll
        for (int d = 0; d < 64; ++d)
            acc += __bfloat162float(q[d]) * __bfloat162float(k[d]);
        int rel = (((i >> 1) - (j >> 1)) + 1) * 3 + (((i & 1) - (j & 1)) + 1);
        sS[h][i][j] = acc * 0.125f + rpb[rel * NH + h];
    }
    __syncthreads();
    if (tid < 32) {
        int h = tid >> 2, i = tid & 3;
        float s0 = sS[h][i][0], s1 = sS[h][i][1], s2 = sS[h][i][2], s3 = sS[h][i][3];
        float mx = fmaxf(fmaxf(s0, s1), fmaxf(s2, s3));
        float e0 = expf(s0 - mx), e1 = expf(s1 - mx), e2 = expf(s2 - mx), e3 = expf(s3 - mx);
        float inv = 1.f / (e0 + e1 + e2 + e3);
        sP[h][i][0] = e0 * inv; sP[h][i][1] = e1 * inv;
        sP[h][i][2] = e2 * inv; sP[h][i][3] = e3 * inv;
    }
    __syncthreads();
    {
        int h = tid >> 5, tl = tid & 31;
        int d = tl * 2;
        const bf16* v = &sT[1024 + h * 64 + d];
#pragma unroll
        for (int i = 0; i < 4; ++i) {
            float p0 = sP[h][i][0], p1 = sP[h][i][1], p2 = sP[h][i][2], p3 = sP[h][i][3];
            float o0 = p0 * __bfloat162float(v[0])        + p1 * __bfloat162float(v[1536])
                     + p2 * __bfloat162float(v[2 * 1536]) + p3 * __bfloat162float(v[3 * 1536]);
            float o1 = p0 * __bfloat162float(v[1])            + p1 * __bfloat162float(v[1536 + 1])
                     + p2 * __bfloat162float(v[2 * 1536 + 1]) + p3 * __bfloat162float(v[3 * 1536 + 1]);
            __hip_bfloat162 pr;
            pr.x = __float2bfloat16(o0);
            pr.y = __float2bfloat16(o1);
            *(__hip_bfloat162*)&o[(size_t)(b * 4 + i) * CH + h * 64 + d] = pr;
        }
    }
}

extern "C" void kernel_launch(void* const* d_in, const int* in_sizes, int n_in,
                              void* d_out, int out_size, void* d_ws, size_t ws_size,
                              hipStream_t stream) {
    const float* x      = (const float*)d_in[0];
    const float* ln_g   = (const float*)d_in[1];
    const float* ln_b   = (const float*)d_in[2];
    const float* qkv_w  = (const float*)d_in[3];
    const float* proj_w = (const float*)d_in[4];
    const float* proj_b = (const float*)d_in[5];
    const float* rpb    = (const float*)d_in[6];
    const float* fc1_w  = (const float*)d_in[7];
    const float* fc1_b  = (const float*)d_in[8];
    const float* fc2_w  = (const float*)d_in[9];
    const float* fc2_b  = (const float*)d_in[10];
    float* out = (float*)d_out;

    char* ws = (char*)d_ws;
    bf16* wQKV  = (bf16*)ws;  ws += (size_t)1536 * 512 * 2;
    bf16* wPROJ = (bf16*)ws;  ws += (size_t)512  * 512 * 2;
    bf16* wFC1  = (bf16*)ws;  ws += (size_t)2048 * 512 * 2;
    bf16* wFC2  = (bf16*)ws;  ws += (size_t)512 * 2048 * 2;
    bf16* hA    = (bf16*)ws;  ws += (size_t)NTOK * 512 * 2;   // 64 MB
    bf16* big   = (bf16*)ws;  ws += (size_t)NTOK * 2048 * 2;  // 256 MB
    bf16* x1b   = (bf16*)ws;                                  // optional 64 MB
    const size_t needed  = 6291456ull + 67108864ull + 268435456ull;
    const size_t needed2 = needed + 67108864ull;
    if (ws_size < needed) return;
    const bool useb = (ws_size >= needed2);

    packall<<<1536, 256, 0, stream>>>(qkv_w, proj_w, fc1_w, fc2_w,
                                      wQKV, wPROJ, wFC1, wFC2);

    // LN1: x -> hA
    ln_kernel<0><<<NTOK / 4, 256, 0, stream>>>(x, ln_g, ln_b, hA);
    // qkv = hA @ qkv_w^T -> big
    gemm256x128<0><<<dim3(256 * 12), 512, 0, stream>>>(
        hA, wQKV, NTOK, 1536, 512, 12, nullptr, nullptr, nullptr, nullptr, big);
    // attention: big -> hA (o)
    attn_kernel<<<BQ, 256, 0, stream>>>(big, rpb, hA);

    if (useb) {
        // x1 = x + o @ proj_w^T + proj_b -> x1b (bf16)
        gemm256x128<3><<<dim3(256 * 4), 512, 0, stream>>>(
            hA, wPROJ, NTOK, 512, 512, 4, proj_b, x, nullptr, nullptr, x1b);
        ln_kernel<1><<<NTOK / 4, 256, 0, stream>>>(x1b, ln_g, ln_b, hA);
        // g = gelu(h2 @ fc1_w^T + fc1_b) -> big, via gemm64 (256x256, BK=64)
        gemm64<2><<<dim3(256 * 8), 512, 0, stream>>>(
            hA, wFC1, NTOK, 2048, 512, 8, fc1_b, nullptr, nullptr, nullptr, big);
        // out = x1b + g @ fc2_w^T + fc2_b, via gemm64
        gemm64<4><<<dim3(256 * 2), 512, 0, stream>>>(
            big, wFC2, NTOK, 512, 2048, 2, fc2_b, nullptr, x1b, out, nullptr);
    } else {
        gemm256x128<1><<<dim3(256 * 4), 512, 0, stream>>>(
            hA, wPROJ, NTOK, 512, 512, 4, proj_b, x, nullptr, out, nullptr);
        ln_kernel<0><<<NTOK / 4, 256, 0, stream>>>(out, ln_g, ln_b, hA);
        gemm64<2><<<dim3(256 * 8), 512, 0, stream>>>(
            hA, wFC1, NTOK, 2048, 512, 8, fc1_b, nullptr, nullptr, nullptr, big);
        gemm64<1><<<dim3(256 * 2), 512, 0, stream>>>(
            big, wFC2, NTOK, 512, 2048, 2, fc2_b, out, nullptr, out, nullptr);
    }
}

// Round 21
// 726.990 us; speedup vs baseline: 1.0246x; 1.0246x over previous
//
#include <hip/hip_runtime.h>
#include <hip/hip_bf16.h>
#include <math.h>

// Problem constants
#define BQ   16384        // windows
#define CH   512
#define NH   8
#define HID  2048
#define NTOK (BQ*4)       // 65536 rows

using bf16 = __hip_bfloat16;
typedef __bf16 bf16x8 __attribute__((ext_vector_type(8)));
typedef float  f32x4  __attribute__((ext_vector_type(4)));

#define FENCE() asm volatile("" ::: "memory")

__device__ __forceinline__ void gload16(const void* g, void* l) {
    __builtin_amdgcn_global_load_lds(
        (const __attribute__((address_space(1))) void*)g,
        (__attribute__((address_space(3))) void*)l, 16, 0, 0);
}

// ---------------- weight packs ----------------------------------------------
// OLD format (qkv/proj/fc1, for gemm256x128): 8KB slab per (cb of 128 rows, K-32)
__device__ __forceinline__ void packw_one(const float* Wsrc, bf16* out, int q, int K) {
    int NSk = K >> 5;
    int l  = q & 63;
    int jj = (q >> 6) & 1;
    int w  = (q >> 7) & 3;
    int s  = (q >> 9) % NSk;
    int cb = q / (NSk * 512);
    int row = cb * 128 + w * 32 + jj * 16 + (l >> 2);
    int k   = s * 32 + ((l & 3) ^ ((l >> 3) & 3)) * 8;
    const float* src = Wsrc + (size_t)row * K + k;
    float4 v0 = *(const float4*)src;
    float4 v1 = *(const float4*)(src + 4);
    __align__(16) bf16 t[8];
    t[0] = __float2bfloat16(v0.x); t[1] = __float2bfloat16(v0.y);
    t[2] = __float2bfloat16(v0.z); t[3] = __float2bfloat16(v0.w);
    t[4] = __float2bfloat16(v1.x); t[5] = __float2bfloat16(v1.y);
    t[6] = __float2bfloat16(v1.z); t[7] = __float2bfloat16(v1.w);
    *(uint4*)&out[(size_t)q * 8] = *(const uint4*)t;
}

// NEW format (fc2 only, for gemm64): 16KB B-half slab per (cb of 256, kt of 64, h)
__device__ __forceinline__ void pack64_one(const float* Wsrc, bf16* out, int q, int K) {
    int NKT = K >> 6;
    int j  = q & 7;
    int r  = (q >> 3) & 127;
    int h  = (q >> 10) & 1;
    int kt = (q >> 11) % NKT;
    int cb = q / (NKT << 11);
    int row = cb * 256 + h * 128 + r;
    int col = kt * 64 + (j ^ (r & 7)) * 8;
    const float* src = Wsrc + (size_t)row * K + col;
    float4 v0 = *(const float4*)src;
    float4 v1 = *(const float4*)(src + 4);
    __align__(16) bf16 t[8];
    t[0] = __float2bfloat16(v0.x); t[1] = __float2bfloat16(v0.y);
    t[2] = __float2bfloat16(v0.z); t[3] = __float2bfloat16(v0.w);
    t[4] = __float2bfloat16(v1.x); t[5] = __float2bfloat16(v1.y);
    t[6] = __float2bfloat16(v1.z); t[7] = __float2bfloat16(v1.w);
    *(uint4*)&out[(size_t)q * 8] = *(const uint4*)t;
}

// chunk counts: qkv 98304, proj 32768, fc1 131072 (old); fc2 131072 (new) = 393216
__global__ __launch_bounds__(256)
void packall(const float* qkv_w, const float* proj_w,
             const float* fc1_w, const float* fc2_w,
             bf16* wQKV, bf16* wPROJ, bf16* wFC1, bf16* wFC2) {
    int q = blockIdx.x * 256 + threadIdx.x;
    if (q < 98304)            packw_one(qkv_w,  wQKV,  q,           512);
    else if (q < 131072)      packw_one(proj_w, wPROJ, q - 98304,   512);
    else if (q < 262144)      packw_one(fc1_w,  wFC1,  q - 131072,  512);
    else                      pack64_one(fc2_w, wFC2,  q - 262144, 2048);
}

// ---------------- LayerNorm (fp32 or bf16 in, bf16 out), one wave per row ------
template<int BF16IN>
__global__ __launch_bounds__(256) void ln_kernel(const void* __restrict__ xin,
                                                 const float* __restrict__ g,
                                                 const float* __restrict__ b,
                                                 bf16* __restrict__ out) {
    int row  = blockIdx.x * 4 + (threadIdx.x >> 6);
    int lane = threadIdx.x & 63;
    int c0 = lane * 8;
    float f[8];
    if (BF16IN) {
        const bf16* xr = (const bf16*)xin + (size_t)row * CH;
        union { uint4 u4; bf16 h[8]; } uu;
        uu.u4 = *(const uint4*)&xr[c0];
#pragma unroll
        for (int i = 0; i < 8; ++i) f[i] = __bfloat162float(uu.h[i]);
    } else {
        const float* xr = (const float*)xin + (size_t)row * CH;
        float4 v0 = *(const float4*)&xr[c0];
        float4 v1 = *(const float4*)&xr[c0 + 4];
        f[0]=v0.x; f[1]=v0.y; f[2]=v0.z; f[3]=v0.w;
        f[4]=v1.x; f[5]=v1.y; f[6]=v1.z; f[7]=v1.w;
    }
    float s = 0.f, sq = 0.f;
#pragma unroll
    for (int i = 0; i < 8; ++i) { s += f[i]; sq += f[i] * f[i]; }
#pragma unroll
    for (int off = 32; off >= 1; off >>= 1) {
        s  += __shfl_xor(s,  off, 64);
        sq += __shfl_xor(sq, off, 64);
    }
    float mu  = s * (1.0f / CH);
    float var = sq * (1.0f / CH) - mu * mu;
    float rs  = rsqrtf(var + 1e-5f);
    float4 g0 = *(const float4*)&g[c0];
    float4 g1 = *(const float4*)&g[c0 + 4];
    float4 b0 = *(const float4*)&b[c0];
    float4 b1 = *(const float4*)&b[c0 + 4];
    float gg[8] = {g0.x,g0.y,g0.z,g0.w,g1.x,g1.y,g1.z,g1.w};
    float bb[8] = {b0.x,b0.y,b0.z,b0.w,b1.x,b1.y,b1.z,b1.w};
    __align__(16) bf16 t[8];
#pragma unroll
    for (int i = 0; i < 8; ++i)
        t[i] = __float2bfloat16((f[i] - mu) * rs * gg[i] + bb[i]);
    *(uint4*)&out[(size_t)row * CH + c0] = *(const uint4*)t;
}

// ---------------- GEMM 256x128 tile (proven; best for K=512 shapes) ------------
template<int EPI>
__global__ __launch_bounds__(512, 4)
void gemm256x128(const bf16* __restrict__ A, const bf16* __restrict__ Bp,
                 int M, int N, int K, int nbx,
                 const float* __restrict__ bias,
                 const float* residF, const bf16* residB,
                 float* outF, bf16* __restrict__ outB) {
    __shared__ __align__(16) char lds[49152];
    const int tid  = threadIdx.x;
    const int w    = tid >> 6;
    const int lane = tid & 63;
    const int nb  = gridDim.x;
    const int id  = blockIdx.x;
    const int swz = (id & 7) * (nb >> 3) + (id >> 3);
    const int bx  = swz % nbx, by = swz / nbx;
    const int bm = by * 256, bn = bx * 128;
    const int wrq = w >> 1;
    const int wch = w & 1;
    const int NSk = K >> 5;

    const int rl  = lane >> 2;
    const int kpe = ((lane & 3) ^ ((lane >> 3) & 3)) * 8;
    const bf16* gA0 = A + (size_t)(bm + w * 32 + rl) * K + kpe;
    const bf16* gA1 = gA0 + (size_t)16 * K;
    const bf16* gB = Bp + (size_t)(bn >> 7) * NSk * 4096 + w * 512 + lane * 8;

    const int kslot = ((lane >> 4) ^ ((lane >> 1) & 3));
    const int aoff = (wrq * 64 + (lane & 15)) * 64 + kslot * 16;
    const int boff = 16384 + (wch * 64 + (lane & 15)) * 64 + kslot * 16;

    f32x4 acc[4][4] = {};

    auto stage = [&](int s) {
        char* base = (char*)lds + (s & 1) * 24576;
        gload16(gA0 + (size_t)s * 32, base + w * 2048);
        gload16(gA1 + (size_t)s * 32, base + w * 2048 + 1024);
        gload16(gB  + (size_t)s * 4096, base + 16384 + w * 1024);
    };

    auto compute = [&](int slot) {
        const char* base = (const char*)lds + slot * 24576;
        bf16x8 av[4], bv[4];
#pragma unroll
        for (int n = 0; n < 4; ++n)
            bv[n] = *(const bf16x8*)(base + boff + n * 1024);
#pragma unroll
        for (int m = 0; m < 4; ++m)
            av[m] = *(const bf16x8*)(base + aoff + m * 1024);
#pragma unroll
        for (int m = 0; m < 4; ++m)
#pragma unroll
            for (int n = 0; n < 4; ++n)
                acc[m][n] = __builtin_amdgcn_mfma_f32_16x16x32_bf16(av[m], bv[n], acc[m][n], 0, 0, 0);
    };

#define WAITV(n) asm volatile("s_waitcnt vmcnt(" #n ")" ::: "memory")
    stage(0);
    for (int s = 0; s < NSk - 1; ++s) {
        stage(s + 1);
        WAITV(3);
        __builtin_amdgcn_s_barrier();
        FENCE();
        compute(s & 1);
        FENCE();
        __builtin_amdgcn_s_barrier();
    }
    WAITV(0);
    __builtin_amdgcn_s_barrier();
    FENCE();
    compute((NSk - 1) & 1);
#undef WAITV

    const int erow0 = bm + wrq * 64 + (lane >> 4) * 4;
    const int ecol0 = bn + wch * 64 + (lane & 15);
#pragma unroll
    for (int m = 0; m < 4; ++m) {
#pragma unroll
        for (int n = 0; n < 4; ++n) {
            int col = ecol0 + n * 16;
#pragma unroll
            for (int r = 0; r < 4; ++r) {
                int row = erow0 + m * 16 + r;
                size_t idx = (size_t)row * N + col;
                float v = acc[m][n][r];
                if (EPI == 0) {
                    outB[idx] = __float2bfloat16(v);
                } else if (EPI == 1) {
                    outF[idx] = v + bias[col] + residF[idx];
                } else if (EPI == 2) {
                    float t = v + bias[col];
                    float u2 = 1.5957691216f * t * (1.0f + 0.044715f * t * t);
                    float e = __expf(u2);
                    float rcp = __builtin_amdgcn_rcpf(e + 1.0f);
                    outB[idx] = __float2bfloat16(t - t * rcp);
                } else if (EPI == 3) {
                    outB[idx] = __float2bfloat16(v + bias[col] + residF[idx]);
                } else {
                    outF[idx] = v + bias[col] + __bfloat162float(residB[idx]);
                }
            }
        }
    }
}

// ---------------- GEMM64: 256x256, BK=64 (verified R19; best for K=2048) -------
template<int EPI>
__global__ __launch_bounds__(512, 2)
void gemm64(const bf16* __restrict__ A, const bf16* __restrict__ Bp,
            int M, int N, int K, int nbx,
            const float* __restrict__ bias,
            const float* residF, const bf16* residB,
            float* outF, bf16* __restrict__ outB) {
    __shared__ __align__(16) char lds[131072];
    const int tid  = threadIdx.x;
    const int w    = tid >> 6;     // wave 0..7
    const int lane = tid & 63;

    const int nb  = gridDim.x;
    const int id  = blockIdx.x;
    const int swz = (id & 7) * (nb >> 3) + (id >> 3);
    const int bx  = swz % nbx, by = swz / nbx;
    const int bm = by * 256, bn = bx * 256;
    const int wr = w >> 2;         // 0..1 (M half of 128 rows)
    const int wc = w & 3;          // 0..3 (N quarter of 64 cols)
    const int NT = K >> 6;         // K/64 tiles (>= 4)

    const bf16* gA0 = A + (size_t)(bm + w * 16 + (lane >> 3)) * K
                        + ((lane & 7) ^ ((lane >> 3) & 7)) * 8;
    const bf16* gB0 = Bp + (size_t)(bn >> 8) * NT * 16384 + w * 1024 + lane * 8;

    const int abase_off = wr * 16384 + (lane & 15) * 128;
    const int bbase_off = 32768 + (wc >> 1) * 16384 + ((wc & 1) * 64 + (lane & 15)) * 128;
    const int aj0 = (((lane >> 4)    ) ^ (lane & 7)) * 16;
    const int aj1 = (((lane >> 4) + 4) ^ (lane & 7)) * 16;

    f32x4 acc[8][4] = {};
    bf16x8 av[4][2], bv[2][2], bw[2][2];

    auto stA = [&](int X, int ah) {
        char* d = (char*)lds + (X & 1) * 65536 + ah * 16384 + w * 2048;
        const bf16* s = gA0 + (size_t)ah * 128 * K + (size_t)X * 64;
        gload16(s, d);
        gload16(s + (size_t)8 * K, d + 1024);
    };
    auto stB = [&](int X, int bh) {
        char* d = (char*)lds + (X & 1) * 65536 + 32768 + bh * 16384 + w * 2048;
        const bf16* s = gB0 + ((size_t)X * 2 + bh) * 8192;
        gload16(s, d);
        gload16(s + 512, d + 1024);
    };

#define RD_A(MH) { const char* _p = bb + abase_off + (MH) * 8192;            \
    _Pragma("unroll") for (int _m = 0; _m < 4; ++_m) {                       \
        av[_m][0] = *(const bf16x8*)(_p + _m * 2048 + aj0);                  \
        av[_m][1] = *(const bf16x8*)(_p + _m * 2048 + aj1); } }
#define RD_B(BV, NB) { const char* _p = bb + bbase_off + (NB) * 2048;        \
    BV[0][0] = *(const bf16x8*)(_p + aj0);                                   \
    BV[0][1] = *(const bf16x8*)(_p + aj1);                                   \
    BV[1][0] = *(const bf16x8*)(_p + 2048 + aj0);                            \
    BV[1][1] = *(const bf16x8*)(_p + 2048 + aj1); }
#define MQ(BV, MB, NB) { __builtin_amdgcn_s_setprio(1);                      \
    _Pragma("unroll") for (int _m = 0; _m < 4; ++_m)                         \
    _Pragma("unroll") for (int _n = 0; _n < 2; ++_n) {                       \
        acc[(MB)+_m][(NB)+_n] = __builtin_amdgcn_mfma_f32_16x16x32_bf16(     \
            av[_m][0], BV[_n][0], acc[(MB)+_m][(NB)+_n], 0, 0, 0);           \
        acc[(MB)+_m][(NB)+_n] = __builtin_amdgcn_mfma_f32_16x16x32_bf16(     \
            av[_m][1], BV[_n][1], acc[(MB)+_m][(NB)+_n], 0, 0, 0); }         \
    __builtin_amdgcn_s_setprio(0); }
#define WAITV2() asm volatile("s_waitcnt vmcnt(2)" ::: "memory")
#define WAITV0() asm volatile("s_waitcnt vmcnt(0)" ::: "memory")
#define SBAR()   __builtin_amdgcn_s_barrier()
#define LGKM0()  asm volatile("s_waitcnt lgkmcnt(0)" ::: "memory")

#define ITER_BODY(T, DO_ST1, DO_ST2, TAILW)                                  \
    { const char* bb = (const char*)lds + ((T) & 1) * 65536;                 \
      RD_A(0); RD_B(bv, 0); FENCE();                                        \
      if (DO_ST1) stA((T) + 1, 1);                                           \
      SBAR(); LGKM0(); MQ(bv, 0, 0); SBAR();                                 \
      RD_B(bw, 2); FENCE();                                                  \
      if (DO_ST1) stB((T) + 1, 0);                                           \
      SBAR(); LGKM0(); MQ(bw, 0, 2); SBAR();                                 \
      RD_A(1); FENCE();                                                      \
      if (DO_ST1) stB((T) + 1, 1);                                           \
      SBAR(); LGKM0(); MQ(bv, 4, 0); SBAR();                                 \
      if (DO_ST2) stA((T) + 2, 0);                                           \
      MQ(bw, 4, 2);                                                          \
      TAILW; SBAR(); }

    stA(0, 0); stA(0, 1); stB(0, 0); stB(0, 1); stA(1, 0);
    WAITV2(); SBAR();

    for (int t = 0; t < NT - 2; ++t)
        ITER_BODY(t, true, true, WAITV2())
    ITER_BODY(NT - 2, true, false, WAITV0())
    {
        const char* bb = (const char*)lds + ((NT - 1) & 1) * 65536;
        RD_A(0); RD_B(bv, 0); FENCE();
        SBAR(); LGKM0(); MQ(bv, 0, 0); SBAR();
        RD_B(bw, 2); FENCE();
        SBAR(); LGKM0(); MQ(bw, 0, 2); SBAR();
        RD_A(1); FENCE();
        SBAR(); LGKM0(); MQ(bv, 4, 0); SBAR();
        MQ(bw, 4, 2);
    }
#undef RD_A
#undef RD_B
#undef MQ
#undef WAITV2
#undef WAITV0
#undef SBAR
#undef LGKM0
#undef ITER_BODY

    const int erow0 = bm + wr * 128 + (lane >> 4) * 4;
    const int ecol0 = bn + wc * 64 + (lane & 15);
#pragma unroll
    for (int m = 0; m < 8; ++m) {
#pragma unroll
        for (int n = 0; n < 4; ++n) {
            int col = ecol0 + n * 16;
#pragma unroll
            for (int r = 0; r < 4; ++r) {
                int row = erow0 + m * 16 + r;
                size_t idx = (size_t)row * N + col;
                float v = acc[m][n][r];
                if (EPI == 1) {
                    outF[idx] = v + bias[col] + residF[idx];
                } else {  // EPI 4
                    outF[idx] = v + bias[col] + __bfloat162float(residB[idx]);
                }
            }
        }
    }
}

// ---------------- windowed attention: one block per window ----------------
__global__ __launch_bounds__(256)
void attn_kernel(const bf16* __restrict__ qkv, const float* __restrict__ rpb,
                 bf16* __restrict__ o) {
    __shared__ __align__(16) bf16 sT[4 * 1536];
    __shared__ float sS[NH][4][4];
    __shared__ float sP[NH][4][4];
    int b   = blockIdx.x;
    int tid = threadIdx.x;
    const bf16* src = qkv + (size_t)b * (4 * 1536);
#pragma unroll
    for (int it = 0; it < 3; ++it) {
        int e = (it * 256 + tid) * 8;
        *(uint4*)&sT[e] = *(const uint4*)&src[e];
    }
    __syncthreads();
    if (tid < 128) {
        int h = tid >> 4, i = (tid >> 2) & 3, j = tid & 3;
        const bf16* q = &sT[i * 1536 + h * 64];
        const bf16* k = &sT[j * 1536 + 512 + h * 64];
        float acc = 0.f;
#pragma unroll
        for (int d = 0; d < 64; ++d)
            acc += __bfloat162float(q[d]) * __bfloat162float(k[d]);
        int rel = (((i >> 1) - (j >> 1)) + 1) * 3 + (((i & 1) - (j & 1)) + 1);
        sS[h][i][j] = acc * 0.125f + rpb[rel * NH + h];
    }
    __syncthreads();
    if (tid < 32) {
        int h = tid >> 2, i = tid & 3;
        float s0 = sS[h][i][0], s1 = sS[h][i][1], s2 = sS[h][i][2], s3 = sS[h][i][3];
        float mx = fmaxf(fmaxf(s0, s1), fmaxf(s2, s3));
        float e0 = expf(s0 - mx), e1 = expf(s1 - mx), e2 = expf(s2 - mx), e3 = expf(s3 - mx);
        float inv = 1.f / (e0 + e1 + e2 + e3);
        sP[h][i][0] = e0 * inv; sP[h][i][1] = e1 * inv;
        sP[h][i][2] = e2 * inv; sP[h][i][3] = e3 * inv;
    }
    __syncthreads();
    {
        int h = tid >> 5, tl = tid & 31;
        int d = tl * 2;
        const bf16* v = &sT[1024 + h * 64 + d];
#pragma unroll
        for (int i = 0; i < 4; ++i) {
            float p0 = sP[h][i][0], p1 = sP[h][i][1], p2 = sP[h][i][2], p3 = sP[h][i][3];
            float o0 = p0 * __bfloat162float(v[0])        + p1 * __bfloat162float(v[1536])
                     + p2 * __bfloat162float(v[2 * 1536]) + p3 * __bfloat162float(v[3 * 1536]);
            float o1 = p0 * __bfloat162float(v[1])            + p1 * __bfloat162float(v[1536 + 1])
                     + p2 * __bfloat162float(v[2 * 1536 + 1]) + p3 * __bfloat162float(v[3 * 1536 + 1]);
            __hip_bfloat162 pr;
            pr.x = __float2bfloat16(o0);
            pr.y = __float2bfloat16(o1);
            *(__hip_bfloat162*)&o[(size_t)(b * 4 + i) * CH + h * 64 + d] = pr;
        }
    }
}

extern "C" void kernel_launch(void* const* d_in, const int* in_sizes, int n_in,
                              void* d_out, int out_size, void* d_ws, size_t ws_size,
                              hipStream_t stream) {
    const float* x      = (const float*)d_in[0];
    const float* ln_g   = (const float*)d_in[1];
    const float* ln_b   = (const float*)d_in[2];
    const float* qkv_w  = (const float*)d_in[3];
    const float* proj_w = (const float*)d_in[4];
    const float* proj_b = (const float*)d_in[5];
    const float* rpb    = (const float*)d_in[6];
    const float* fc1_w  = (const float*)d_in[7];
    const float* fc1_b  = (const float*)d_in[8];
    const float* fc2_w  = (const float*)d_in[9];
    const float* fc2_b  = (const float*)d_in[10];
    float* out = (float*)d_out;

    char* ws = (char*)d_ws;
    bf16* wQKV  = (bf16*)ws;  ws += (size_t)1536 * 512 * 2;
    bf16* wPROJ = (bf16*)ws;  ws += (size_t)512  * 512 * 2;
    bf16* wFC1  = (bf16*)ws;  ws += (size_t)2048 * 512 * 2;
    bf16* wFC2  = (bf16*)ws;  ws += (size_t)512 * 2048 * 2;
    bf16* hA    = (bf16*)ws;  ws += (size_t)NTOK * 512 * 2;   // 64 MB
    bf16* big   = (bf16*)ws;  ws += (size_t)NTOK * 2048 * 2;  // 256 MB
    bf16* x1b   = (bf16*)ws;                                  // optional 64 MB
    const size_t needed  = 6291456ull + 67108864ull + 268435456ull;
    const size_t needed2 = needed + 67108864ull;
    if (ws_size < needed) return;
    const bool useb = (ws_size >= needed2);

    packall<<<1536, 256, 0, stream>>>(qkv_w, proj_w, fc1_w, fc2_w,
                                      wQKV, wPROJ, wFC1, wFC2);

    // LN1: x -> hA
    ln_kernel<0><<<NTOK / 4, 256, 0, stream>>>(x, ln_g, ln_b, hA);
    // qkv = hA @ qkv_w^T -> big
    gemm256x128<0><<<dim3(256 * 12), 512, 0, stream>>>(
        hA, wQKV, NTOK, 1536, 512, 12, nullptr, nullptr, nullptr, nullptr, big);
    // attention: big -> hA (o)
    attn_kernel<<<BQ, 256, 0, stream>>>(big, rpb, hA);

    if (useb) {
        // x1 = x + o @ proj_w^T + proj_b -> x1b (bf16)
        gemm256x128<3><<<dim3(256 * 4), 512, 0, stream>>>(
            hA, wPROJ, NTOK, 512, 512, 4, proj_b, x, nullptr, nullptr, x1b);
        ln_kernel<1><<<NTOK / 4, 256, 0, stream>>>(x1b, ln_g, ln_b, hA);
        // g = gelu(h2 @ fc1_w^T + fc1_b) -> big  (2-phase kernel: best at K=512)
        gemm256x128<2><<<dim3(256 * 16), 512, 0, stream>>>(
            hA, wFC1, NTOK, 2048, 512, 16, fc1_b, nullptr, nullptr, nullptr, big);
        // out = x1b + g @ fc2_w^T + fc2_b  (gemm64: best at K=2048)
        gemm64<4><<<dim3(256 * 2), 512, 0, stream>>>(
            big, wFC2, NTOK, 512, 2048, 2, fc2_b, nullptr, x1b, out, nullptr);
    } else {
        gemm256x128<1><<<dim3(256 * 4), 512, 0, stream>>>(
            hA, wPROJ, NTOK, 512, 512, 4, proj_b, x, nullptr, out, nullptr);
        ln_kernel<0><<<NTOK / 4, 256, 0, stream>>>(out, ln_g, ln_b, hA);
        gemm256x128<2><<<dim3(256 * 16), 512, 0, stream>>>(
            hA, wFC1, NTOK, 2048, 512, 16, fc1_b, nullptr, nullptr, nullptr, big);
        gemm64<1><<<dim3(256 * 2), 512, 0, stream>>>(
            big, wFC2, NTOK, 512, 2048, 2, fc2_b, out, nullptr, out, nullptr);
    }
}